// Round 15
// baseline (354.462 us; speedup 1.0000x reference)
//
#include <hip/hip_runtime.h>

#define Bb 2
#define Nn 50000
#define Ee 512000
#define DE 128
#define HH 256
#define DO 128
#define TILES32 1563     // ceil(50000/32)
#define CAP 48           // per-node edge-list capacity (Poisson(10.24) max deg ~35)
#define NCNT (Bb * Nn)   // 100,000 nodes; cnt[NCNT] is the spill counter
#define SPILL_MAX 65536

typedef __attribute__((ext_vector_type(8))) short short8;
typedef __attribute__((ext_vector_type(4))) float f32x4;

// Agent-scope atomic store: lay down the zeros that later atomicAdds RMW
// (round-3: plain-stored zeros + cross-kernel atomic RMW diverged in replay).
#define ATOMIC_ST(p, v) __hip_atomic_store((p), (v), __ATOMIC_RELAXED, __HIP_MEMORY_SCOPE_AGENT)

// f32 -> bf16 round-to-nearest-even (data has no NaN/Inf)
static __device__ __forceinline__ unsigned short f2bf(float f) {
  union { float f; unsigned int u; } x; x.f = f;
  return (unsigned short)((x.u + 0x7FFFu + ((x.u >> 16) & 1u)) >> 16);
}

// Init: W1/W2 -> bf16 MFMA B-fragment order, AND zero cnt[] (merged launch).
__global__ void init_kernel(const float* __restrict__ W1, const float* __restrict__ W2,
                            unsigned short* __restrict__ w1f, unsigned short* __restrict__ w2f,
                            int* __restrict__ cnt) {
  int t = blockIdx.x * 256 + threadIdx.x;
  if (t < 16 * 8 * 64) {
    int lane = t & 63, ks = (t >> 6) & 7, ct = t >> 9;
    int col = ct * 16 + (lane & 15);
    int k0 = ks * 32 + (lane >> 4) * 8;
    for (int j = 0; j < 8; ++j)
      w1f[t * 8 + j] = f2bf(W1[(k0 + j) * HH + col]);
  }
  if (t < 8 * 8 * 64) {
    int lane = t & 63, ks = (t >> 6) & 7, ct = t >> 9;
    int col = ct * 16 + (lane & 15);
    int k0 = ks * 32 + (lane >> 4) * 8;
    for (int j = 0; j < 8; ++j)
      w2f[t * 8 + j] = f2bf(W2[(k0 + j) * DO + col]);
  }
  if (t <= NCNT) ATOMIC_ST(&cnt[t], 0);
}

// Build per-node edge lists: TWO edges per thread (int2 recv load) to halve
// the launch; one int atomic per edge; plain ids stores (round-2/5-proven).
__global__ void fill_kernel(const int* __restrict__ recv, int* __restrict__ cnt,
                            int* __restrict__ ids, int* __restrict__ spill) {
  int t = blockIdx.x * 256 + threadIdx.x;   // grid sized to exactly Bb*Ee/2
  int i0 = t * 2;
  int2 rr = *reinterpret_cast<const int2*>(&recv[i0]);
#pragma unroll
  for (int k = 0; k < 2; ++k) {
    int i = i0 + k;
    int r = k ? rr.y : rr.x;
    int node = ((i >= Ee) ? Nn : 0) + r;
    int pos = atomicAdd(&cnt[node], 1);
    if (pos < CAP) {
      ids[(long)node * CAP + pos] = i;  // GLOBAL edge index
    } else {
      int s = atomicAdd(&cnt[NCNT], 1);
      if (s < SPILL_MAX) spill[s] = i;
    }
  }
}

// Gather-sum at the random-512B-touch wall (~4 G touches/s measured across
// rounds 5/8/9/10/12/13; every materialization alternative doubles touches
// and loses). ONE HALF-WAVE PER NODE; ids as int4 pairs -> EIGHT independent
// 512B edge-row loads in flight (tests whether round-8's ILP-4 still left
// per-half-wave queue depth on the table). No LDS, low VGPR, 8 waves/SIMD.
__global__ __launch_bounds__(256, 8) void gather_kernel(
    const float4* __restrict__ edge4, const int* __restrict__ cnt,
    const int* __restrict__ ids, const int* __restrict__ spill,
    const int* __restrict__ recv, unsigned short* __restrict__ aggb) {
  int half = (blockIdx.x * 256 + threadIdx.x) >> 5;  // global half-wave = node id
  int hl = threadIdx.x & 31;
  if (half >= NCNT) return;
  const int g = half;
  int deg0 = cnt[g];
  int deg = min(deg0, CAP);
  const int4* p4 = reinterpret_cast<const int4*>(ids + (long)g * CAP);
  float4 acc = make_float4(0.f, 0.f, 0.f, 0.f);

  int i = 0;
  for (; i + 8 <= deg; i += 8) {  // 8 loads in flight
    int4 qa = p4[i >> 2];
    int4 qb = p4[(i >> 2) + 1];
    float4 v0 = edge4[(long)qa.x * 32 + hl];
    float4 v1 = edge4[(long)qa.y * 32 + hl];
    float4 v2 = edge4[(long)qa.z * 32 + hl];
    float4 v3 = edge4[(long)qa.w * 32 + hl];
    float4 v4 = edge4[(long)qb.x * 32 + hl];
    float4 v5 = edge4[(long)qb.y * 32 + hl];
    float4 v6 = edge4[(long)qb.z * 32 + hl];
    float4 v7 = edge4[(long)qb.w * 32 + hl];
    acc.x += ((v0.x + v1.x) + (v2.x + v3.x)) + ((v4.x + v5.x) + (v6.x + v7.x));
    acc.y += ((v0.y + v1.y) + (v2.y + v3.y)) + ((v4.y + v5.y) + (v6.y + v7.y));
    acc.z += ((v0.z + v1.z) + (v2.z + v3.z)) + ((v4.z + v5.z) + (v6.z + v7.z));
    acc.w += ((v0.w + v1.w) + (v2.w + v3.w)) + ((v4.w + v5.w) + (v6.w + v7.w));
  }
  if (i + 4 <= deg) {  // 4-wide tail
    int4 q = p4[i >> 2];
    float4 v0 = edge4[(long)q.x * 32 + hl];
    float4 v1 = edge4[(long)q.y * 32 + hl];
    float4 v2 = edge4[(long)q.z * 32 + hl];
    float4 v3 = edge4[(long)q.w * 32 + hl];
    acc.x += (v0.x + v1.x) + (v2.x + v3.x);
    acc.y += (v0.y + v1.y) + (v2.y + v3.y);
    acc.z += (v0.z + v1.z) + (v2.z + v3.z);
    acc.w += (v0.w + v1.w) + (v2.w + v3.w);
    i += 4;
  }
  for (; i < deg; ++i) {  // scalar tail
    int e = ids[(long)g * CAP + i];
    float4 v = edge4[(long)e * 32 + hl];
    acc.x += v.x; acc.y += v.y; acc.z += v.z; acc.w += v.w;
  }
  // rare overflow: this node's extra edges sit in the spill list
  if (deg0 > CAP) {
    int sn = min(cnt[NCNT], SPILL_MAX);
    for (int s = 0; s < sn; ++s) {
      int e = spill[s];
      int nb = (e >= Ee) ? 1 : 0;
      if (nb * Nn + recv[e] == g) {
        float4 v = edge4[(long)e * 32 + hl];
        acc.x += v.x; acc.y += v.y; acc.z += v.z; acc.w += v.w;
      }
    }
  }
  ushort4 o;
  o.x = f2bf(acc.x); o.y = f2bf(acc.y); o.z = f2bf(acc.z); o.w = f2bf(acc.w);
  reinterpret_cast<ushort4*>(aggb)[(long)g * 32 + hl] = o;
}

// MLP (round-14-proven): 32-row tile, 128-thread blocks, 16KB LDS.
__global__ __launch_bounds__(128, 4) void mlp_kernel(
    const unsigned short* __restrict__ aggb, const float* __restrict__ node,
    const unsigned short* __restrict__ w1f, const unsigned short* __restrict__ w2f,
    const float* __restrict__ b1, const float* __restrict__ b2,
    float* __restrict__ out) {
  __shared__ __align__(16) char lds[32 * 512];  // 32 rows x 256 cols bf16
  const int tid = threadIdx.x;
  const int lane = tid & 63;
  const int wv = tid >> 6;          // 0..1
  const int blk = blockIdx.x;
  const int b = blk / TILES32;
  const int tile = blk - b * TILES32;
  const int row0 = tile * 32;
  const int rows = min(32, Nn - row0);

  // ---- stage vtin: agg half is already bf16; node half converts ----
#pragma unroll
  for (int ii = 0; ii < 8; ++ii) {  // cols 0..127 from aggb
    int idx = ii * 128 + tid;
    int row = idx >> 5;
    int c4 = idx & 31;
    ushort4 p = make_ushort4(0, 0, 0, 0);
    if (row < rows)
      p = reinterpret_cast<const ushort4*>(aggb)[((long)b * Nn + row0 + row) * 32 + c4];
    int byte = row * 512 + ((c4 * 8) ^ ((row & 7) << 4));
    *reinterpret_cast<ushort4*>(&lds[byte]) = p;
  }
#pragma unroll
  for (int ii = 0; ii < 8; ++ii) {  // cols 128..255 from node_data
    int idx = ii * 128 + tid;
    int row = idx >> 5;
    int c4 = idx & 31;
    float4 v = make_float4(0.f, 0.f, 0.f, 0.f);
    if (row < rows)
      v = reinterpret_cast<const float4*>(node)[((long)b * Nn + row0 + row) * 32 + c4];
    ushort4 p;
    p.x = f2bf(v.x); p.y = f2bf(v.y); p.z = f2bf(v.z); p.w = f2bf(v.w);
    int byte = row * 512 + ((256 + c4 * 8) ^ ((row & 7) << 4));
    *reinterpret_cast<ushort4*>(&lds[byte]) = p;
  }
  __syncthreads();

  // ---- GEMM1: h = relu(vtin @ W1 + b1) ----
  f32x4 acc[16];
#pragma unroll
  for (int ct = 0; ct < 16; ++ct) acc[ct] = (f32x4){0.f, 0.f, 0.f, 0.f};
  const int arow = wv * 16 + (lane & 15);
  const int abase = arow * 512;
  const int aswz = (arow & 7) << 4;
  const int koff = (lane >> 4) * 16;
#pragma unroll
  for (int ks = 0; ks < 8; ++ks) {
    short8 a = *reinterpret_cast<const short8*>(&lds[abase + ((ks * 64 + koff) ^ aswz)]);
#pragma unroll
    for (int ct = 0; ct < 16; ++ct) {
      short8 bf = *reinterpret_cast<const short8*>(w1f + ((ct * 8 + ks) * 64 + lane) * 8);
      acc[ct] = __builtin_amdgcn_mfma_f32_16x16x32_bf16(a, bf, acc[ct], 0, 0, 0);
    }
  }
  __syncthreads();  // both waves done reading vtin before overwrite

  // ---- bias + relu, write h (bf16, swizzled) ----
  {
    const int colb = lane & 15;
    const int rb = wv * 16 + (lane >> 4) * 4;
#pragma unroll
    for (int ct = 0; ct < 16; ++ct) {
      float bias = b1[ct * 16 + colb];
#pragma unroll
      for (int j = 0; j < 4; ++j) {
        float hv = acc[ct][j] + bias;
        hv = hv > 0.f ? hv : 0.f;
        int row = rb + j;
        int byte = row * 512 + (((ct * 16 + colb) * 2) ^ ((row & 7) << 4));
        *reinterpret_cast<unsigned short*>(&lds[byte]) = f2bf(hv);
      }
    }
  }
  __syncthreads();

  // ---- GEMM2: out = h @ W2 + b2 ----
  f32x4 acc2[8];
#pragma unroll
  for (int ct = 0; ct < 8; ++ct) acc2[ct] = (f32x4){0.f, 0.f, 0.f, 0.f};
#pragma unroll
  for (int ks = 0; ks < 8; ++ks) {
    short8 a = *reinterpret_cast<const short8*>(&lds[abase + ((ks * 64 + koff) ^ aswz)]);
#pragma unroll
    for (int ct = 0; ct < 8; ++ct) {
      short8 bf = *reinterpret_cast<const short8*>(w2f + ((ct * 8 + ks) * 64 + lane) * 8);
      acc2[ct] = __builtin_amdgcn_mfma_f32_16x16x32_bf16(a, bf, acc2[ct], 0, 0, 0);
    }
  }
  {
    const int colb = lane & 15;
    const int rb = wv * 16 + (lane >> 4) * 4;
#pragma unroll
    for (int ct = 0; ct < 8; ++ct) {
      float bias = b2[ct * 16 + colb];
#pragma unroll
      for (int j = 0; j < 4; ++j) {
        int r = rb + j;
        if (r < rows)
          out[((long)b * Nn + row0 + r) * DO + ct * 16 + colb] = acc2[ct][j] + bias;
      }
    }
  }
}

extern "C" void kernel_launch(void* const* d_in, const int* in_sizes, int n_in,
                              void* d_out, int out_size, void* d_ws, size_t ws_size,
                              hipStream_t stream) {
  const float* edge = (const float*)d_in[0];
  const float* node = (const float*)d_in[1];
  const float* W1   = (const float*)d_in[2];
  const float* b1   = (const float*)d_in[3];
  const float* W2   = (const float*)d_in[4];
  const float* b2   = (const float*)d_in[5];
  const int*   recv = (const int*)d_in[6];
  float* out = (float*)d_out;

  char* ws = (char*)d_ws;
  size_t off = 0;
  unsigned short* w1f = (unsigned short*)(ws + off); off += 131072;
  unsigned short* w2f = (unsigned short*)(ws + off); off += 65536;
  int* cnt   = (int*)(ws + off); off += 400016;                 // (NCNT+1)*4 padded
  int* spill = (int*)(ws + off); off += SPILL_MAX * 4;          // 262,144
  int* ids   = (int*)(ws + off); off += (size_t)NCNT * CAP * 4; // 19,200,000
  unsigned short* aggb = (unsigned short*)(ws + off);           // NCNT*128*2 = 25,600,000

  init_kernel<<<(NCNT + 256) / 256, 256, 0, stream>>>(W1, W2, w1f, w2f, cnt);
  fill_kernel<<<Bb * Ee / 512, 256, 0, stream>>>(recv, cnt, ids, spill);
  gather_kernel<<<NCNT / 8, 256, 0, stream>>>((const float4*)edge, cnt, ids, spill, recv, aggb);
  mlp_kernel<<<Bb * TILES32, 128, 0, stream>>>(aggb, node, w1f, w2f, b1, b2, out);
}